// Round 7
// baseline (112.522 us; speedup 1.0000x reference)
//
#include <hip/hip_runtime.h>
#include <math.h>

// N=1024, X_DIM=HID=Y_DIM=256. 2 launches:
//   K1: layer-1 split-K(x2) MFMA GEMM (R6 proven) + moment partials + zero-init
//   K2: fused layer-2 (dual-head, K=256) + bias/tanh/exp epilogue + rowAcc
//       atomics + ticket-last finalize (no spinning — R4 lesson).
constexpr int KT = 64;   // k sub-tile staged in LDS
constexpr int LSB = 72;  // bf16 LDS row stride: 144 B -> benign banks (R6 proven)

typedef short bf16x8 __attribute__((ext_vector_type(8)));
typedef float f32x4  __attribute__((ext_vector_type(4)));

__device__ __forceinline__ unsigned short f2bf_rne(float f) {
    unsigned u = __float_as_uint(f);
    unsigned r = (u + 0x7fff + ((u >> 16) & 1)) >> 16;
    return (unsigned short)r;
}
__device__ __forceinline__ float bf2f(unsigned short h) {
    return __uint_as_float(((unsigned)h) << 16);
}
__device__ __forceinline__ void split4(float4 v, ushort4& hi, ushort4& lo) {
    hi.x = f2bf_rne(v.x); lo.x = f2bf_rne(v.x - bf2f(hi.x));
    hi.y = f2bf_rne(v.y); lo.y = f2bf_rne(v.y - bf2f(hi.y));
    hi.z = f2bf_rne(v.z); lo.z = f2bf_rne(v.z - bf2f(hi.z));
    hi.w = f2bf_rne(v.w); lo.w = f2bf_rne(v.w - bf2f(hi.w));
}

// ---------------------------------------------------------------------------
// K1 GEMM tile (verbatim R6, proven absmax 0.0): 64x64 tile over K [k0,k0+128),
// MFMA 16x16x32 bf16 split-fp32 (hh + hl + lh).
// ---------------------------------------------------------------------------
__device__ __forceinline__ void gemm_tile_mfma(const float* __restrict__ A0,
                                               const float* __restrict__ B,
                                               const float* __restrict__ bias,
                                               float* __restrict__ C,
                                               int rowBase, int colBase, int k0) {
    const int t = threadIdx.x;
    const int w    = t >> 6;
    const int lane = t & 63;
    const int quad = lane >> 4;
    const int mr   = lane & 15;

    __shared__ __align__(16) unsigned short Ah[64][LSB];
    __shared__ __align__(16) unsigned short Al[64][LSB];
    __shared__ __align__(16) unsigned short Bh[64][LSB];
    __shared__ __align__(16) unsigned short Bl[64][LSB];

    f32x4 acc[4] = {{0.f, 0.f, 0.f, 0.f}, {0.f, 0.f, 0.f, 0.f},
                    {0.f, 0.f, 0.f, 0.f}, {0.f, 0.f, 0.f, 0.f}};

    for (int kt = k0; kt < k0 + 128; kt += KT) {
#pragma unroll
        for (int p = 0; p < 4; p++) {
            int idx = p * 256 + t;
            int r = idx >> 4;
            int k4 = idx & 15;
            float4 av = *(const float4*)&A0[(rowBase + r) * 256 + kt + k4 * 4];
            float4 bv = *(const float4*)&B[(colBase + r) * 256 + kt + k4 * 4];
            ushort4 h4, l4;
            split4(av, h4, l4);
            *(ushort4*)&Ah[r][k4 * 4] = h4;
            *(ushort4*)&Al[r][k4 * 4] = l4;
            split4(bv, h4, l4);
            *(ushort4*)&Bh[r][k4 * 4] = h4;
            *(ushort4*)&Bl[r][k4 * 4] = l4;
        }
        __syncthreads();

#pragma unroll
        for (int kk = 0; kk < KT; kk += 32) {
            int ko = kk + quad * 8;
            bf16x8 ah = *(const bf16x8*)&Ah[w * 16 + mr][ko];
            bf16x8 al = *(const bf16x8*)&Al[w * 16 + mr][ko];
#pragma unroll
            for (int c = 0; c < 4; c++) {
                bf16x8 bh = *(const bf16x8*)&Bh[c * 16 + mr][ko];
                bf16x8 bl = *(const bf16x8*)&Bl[c * 16 + mr][ko];
                acc[c] = __builtin_amdgcn_mfma_f32_16x16x32_bf16(ah, bh, acc[c], 0, 0, 0);
                acc[c] = __builtin_amdgcn_mfma_f32_16x16x32_bf16(ah, bl, acc[c], 0, 0, 0);
                acc[c] = __builtin_amdgcn_mfma_f32_16x16x32_bf16(al, bh, acc[c], 0, 0, 0);
            }
        }
        __syncthreads();
    }

    float bcol[4] = {0.f, 0.f, 0.f, 0.f};
    if (bias) {
#pragma unroll
        for (int c = 0; c < 4; c++) bcol[c] = bias[colBase + c * 16 + mr];
    }
#pragma unroll
    for (int c = 0; c < 4; c++) {
#pragma unroll
        for (int reg = 0; reg < 4; reg++) {
            int rg = rowBase + w * 16 + quad * 4 + reg;
            int cg = colBase + c * 16 + mr;
            C[rg * 256 + cg] = acc[c][reg] + bcol[c];
        }
    }
}

// ---------------------------------------------------------------------------
// K1: layer-1 split-K GEMM (256 blocks) + 4-row moment partials + zero-init
// of rowAcc/tick/out (all consumed only in K2).
// decode: chunk=bid&1, head=(bid>>1)&1, colTile=(bid>>2)&3, rowTile=bid>>4
// ---------------------------------------------------------------------------
__global__ __launch_bounds__(256)
void k1_layer1(const float* __restrict__ x,
               const float* __restrict__ w1m, const float* __restrict__ w1l,
               const float* __restrict__ b1m, const float* __restrict__ b1l,
               float* __restrict__ hm0, float* __restrict__ hm1,
               float* __restrict__ hl0, float* __restrict__ hl1,
               const float* __restrict__ y, const float* __restrict__ z,
               float* __restrict__ pA1, float* __restrict__ pB1,
               float* __restrict__ rowAcc, int* __restrict__ tick,
               float* __restrict__ out) {
    int bid = blockIdx.x;
    int t = threadIdx.x;
    int chunk = bid & 1;
    int head  = (bid >> 1) & 1;
    int colBase = ((bid >> 2) & 3) * 64;
    int rowBase = (bid >> 4) * 64;
    int k0 = chunk * 128;
    const float* Bw = head ? w1l : w1m;
    const float* bias = chunk ? nullptr : (head ? b1l : b1m);
    float* C = head ? (chunk ? hl1 : hl0) : (chunk ? hm1 : hm0);
    gemm_tile_mfma(x, Bw, bias, C, rowBase, colBase, k0);

    // moment partials over rows [4*bid, 4*bid+4)
    float sA = 0.f, sB = 0.f;
    int base = bid * 4 * 256 + t;
#pragma unroll
    for (int j = 0; j < 4; j++) {
        float yv = y[base + j * 256];
        float zv = z[base + j * 256];
        sA += yv * yv + zv * zv;
        sB += yv + zv;
    }
    pA1[bid * 256 + t] = sA;
    pB1[bid * 256 + t] = sB;

    // zero-init for K2
    if (bid < 4) rowAcc[bid * 256 + t] = 0.f;
    if (bid == 4 && t < 32) tick[t] = 0;
    if (bid == 0 && t == 0) out[0] = 0.f;
}

// ---------------------------------------------------------------------------
// K2: fused layer-2 + epilogue. 256 blocks = 32 rowTiles x 8 colTiles.
// Each block: rows [rt*32,+32), cols [ct*32,+32), BOTH heads (K=256).
// Wave w: head=w&1, mtile=w>>1, 2 ntiles. mu/lv exchanged via LDS, then
// term = iv*(Mt - dy^2 - dz^2) summed over cols -> rowAcc atomics ->
// ticket: 8th block per rowTile finalizes relu(row)+mean into out.
// ---------------------------------------------------------------------------
__global__ __launch_bounds__(256)
void k2_fused(const float* __restrict__ hm0, const float* __restrict__ hm1,
              const float* __restrict__ hl0, const float* __restrict__ hl1,
              const float* __restrict__ w2m, const float* __restrict__ w2l,
              const float* __restrict__ b2m, const float* __restrict__ b2l,
              const float* __restrict__ y, const float* __restrict__ z,
              const float* __restrict__ pA1, const float* __restrict__ pB1,
              float* __restrict__ rowAcc, int* __restrict__ tick,
              float* __restrict__ out) {
    const int bid = blockIdx.x;
    const int t = threadIdx.x;
    const int rt = bid >> 3;           // row tile 0..31
    const int ct = bid & 7;            // col tile 0..7
    const int w = t >> 6, lane = t & 63, quad = lane >> 4, mr = lane & 15;
    const int h = w & 1, mt = w >> 1;

    __shared__ __align__(16) unsigned short Apl[2][2][32][LSB]; // [head][hi/lo]
    __shared__ __align__(16) unsigned short Bpl[2][2][32][LSB];
    __shared__ float Cx[2][32][33];    // [head][row][col] exchange
    __shared__ float part[16][32];     // 8 for mA + 8 for mB
    __shared__ float mAf[32], mBf[32];

    // ---- moment fold for this block's 32 cols (pA1/pB1: 256 partial sets) ----
    {
        int c = t & 31, g8 = t >> 5;   // g8 0..7
        int gc = ct * 32 + c;
        float sA = 0.f, sB = 0.f;
        for (int j = 0; j < 32; j++) {
            int s = g8 * 32 + j;
            sA += pA1[s * 256 + gc];
            sB += pB1[s * 256 + gc];
        }
        part[g8][c] = sA;
        part[8 + g8][c] = sB;
    }
    __syncthreads();
    if (t < 32) {
        float sA = 0.f, sB = 0.f;
#pragma unroll
        for (int g = 0; g < 8; g++) { sA += part[g][t]; sB += part[8 + g][t]; }
        mAf[t] = sA * (1.f / 1024.f);  // mean_j (y^2+z^2)
        mBf[t] = sB * (1.f / 1024.f);  // mean_j (y+z)
    }

    f32x4 acc[2] = {{0.f, 0.f, 0.f, 0.f}, {0.f, 0.f, 0.f, 0.f}};

    for (int kt = 0; kt < 256; kt += KT) {
        // ---- stage A (relu(h0+h1), both heads) and B (W2, both heads) ----
#pragma unroll
        for (int p = 0; p < 2; p++) {
            int idx = p * 256 + t;
            int r = idx >> 4;          // 0..31
            int k4 = idx & 15;
            int off  = (rt * 32 + r) * 256 + kt + k4 * 4;
            int boff = (ct * 32 + r) * 256 + kt + k4 * 4;
            float4 m0 = *(const float4*)&hm0[off];
            float4 m1 = *(const float4*)&hm1[off];
            float4 l0 = *(const float4*)&hl0[off];
            float4 l1 = *(const float4*)&hl1[off];
            float4 am, av;
            am.x = fmaxf(m0.x + m1.x, 0.f); am.y = fmaxf(m0.y + m1.y, 0.f);
            am.z = fmaxf(m0.z + m1.z, 0.f); am.w = fmaxf(m0.w + m1.w, 0.f);
            av.x = fmaxf(l0.x + l1.x, 0.f); av.y = fmaxf(l0.y + l1.y, 0.f);
            av.z = fmaxf(l0.z + l1.z, 0.f); av.w = fmaxf(l0.w + l1.w, 0.f);
            float4 bm = *(const float4*)&w2m[boff];
            float4 bv = *(const float4*)&w2l[boff];
            ushort4 h4, l4;
            split4(am, h4, l4);
            *(ushort4*)&Apl[0][0][r][k4 * 4] = h4;
            *(ushort4*)&Apl[0][1][r][k4 * 4] = l4;
            split4(av, h4, l4);
            *(ushort4*)&Apl[1][0][r][k4 * 4] = h4;
            *(ushort4*)&Apl[1][1][r][k4 * 4] = l4;
            split4(bm, h4, l4);
            *(ushort4*)&Bpl[0][0][r][k4 * 4] = h4;
            *(ushort4*)&Bpl[0][1][r][k4 * 4] = l4;
            split4(bv, h4, l4);
            *(ushort4*)&Bpl[1][0][r][k4 * 4] = h4;
            *(ushort4*)&Bpl[1][1][r][k4 * 4] = l4;
        }
        __syncthreads();

#pragma unroll
        for (int kk = 0; kk < KT; kk += 32) {
            int ko = kk + quad * 8;
            bf16x8 ah = *(const bf16x8*)&Apl[h][0][mt * 16 + mr][ko];
            bf16x8 al = *(const bf16x8*)&Apl[h][1][mt * 16 + mr][ko];
#pragma unroll
            for (int nt = 0; nt < 2; nt++) {
                bf16x8 bh = *(const bf16x8*)&Bpl[h][0][nt * 16 + mr][ko];
                bf16x8 bl = *(const bf16x8*)&Bpl[h][1][nt * 16 + mr][ko];
                acc[nt] = __builtin_amdgcn_mfma_f32_16x16x32_bf16(ah, bh, acc[nt], 0, 0, 0);
                acc[nt] = __builtin_amdgcn_mfma_f32_16x16x32_bf16(ah, bl, acc[nt], 0, 0, 0);
                acc[nt] = __builtin_amdgcn_mfma_f32_16x16x32_bf16(al, bh, acc[nt], 0, 0, 0);
            }
        }
        __syncthreads();
    }

    // ---- C exchange with bias (C/D layout: col=lane&15, row=quad*4+reg) ----
    {
        const float* b2 = h ? b2l : b2m;
#pragma unroll
        for (int nt = 0; nt < 2; nt++) {
            int cl = nt * 16 + mr;
            float bb = b2[ct * 32 + cl];
#pragma unroll
            for (int reg = 0; reg < 4; reg++) {
                int rl = mt * 16 + quad * 4 + reg;
                Cx[h][rl][cl] = acc[nt][reg] + bb;
            }
        }
    }
    __syncthreads();

    // ---- epilogue: wave w handles rows [w*8, w*8+8) ----
    {
        int half = lane >> 5;          // 0/1
        int col = lane & 31;
        int gcol = ct * 32 + col;
        float mA = mAf[col], mB = mBf[col];
#pragma unroll
        for (int sub = 0; sub < 4; sub++) {
            int row = w * 8 + sub * 2 + half;
            int grow = rt * 32 + row;
            float m = Cx[0][row][col];
            float lv = tanhf(Cx[1][row][col]);
            float iv = 0.5f * expf(-lv);       // 1/(2*exp(logvar))
            float yv = y[grow * 256 + gcol];
            float zv = z[grow * 256 + gcol];
            float Mt = mA - 2.f * m * mB + 2.f * m * m;
            float dy = m - yv, dz = m - zv;
            float term = iv * (Mt - dy * dy - dz * dz);
#pragma unroll
            for (int msk = 16; msk; msk >>= 1)
                term += __shfl_xor(term, msk, 32);   // sum 32 cols (per half)
            if (col == 0) atomicAdd(&rowAcc[grow], term);
        }
    }

    __threadfence();
    __syncthreads();

    // ---- ticket: 8th block of this rowTile finalizes relu+mean ----
    if (w == 0) {
        int old = 0;
        if (lane == 0) old = atomicAdd(&tick[rt], 1);
        old = __shfl(old, 0, 64);
        if (old == 7) {
            __threadfence();
            float v = 0.f;
            if (lane < 32)
                v = fmaxf(__hip_atomic_load(&rowAcc[rt * 32 + lane],
                                            __ATOMIC_RELAXED,
                                            __HIP_MEMORY_SCOPE_AGENT), 0.f);
#pragma unroll
            for (int msk = 16; msk; msk >>= 1)
                v += __shfl_xor(v, msk, 32);
            if (lane == 0) atomicAdd(out, v * (1.f / 1024.f));
        }
    }
}

// ---------------------------------------------------------------------------
extern "C" void kernel_launch(void* const* d_in, const int* in_sizes, int n_in,
                              void* d_out, int out_size, void* d_ws, size_t ws_size,
                              hipStream_t stream) {
    const float* x   = (const float*)d_in[0];
    const float* y   = (const float*)d_in[1];
    const float* zs  = (const float*)d_in[2];
    const float* w1m = (const float*)d_in[3];
    const float* b1m = (const float*)d_in[4];
    const float* w2m = (const float*)d_in[5];
    const float* b2m = (const float*)d_in[6];
    const float* w1l = (const float*)d_in[7];
    const float* b1l = (const float*)d_in[8];
    const float* w2l = (const float*)d_in[9];
    const float* b2l = (const float*)d_in[10];
    float* out = (float*)d_out;

    char* ws = (char*)d_ws;
    float* pA1    = (float*)(ws);                    // 256x256 f32 = 256 KB
    float* pB1    = (float*)(ws + (256u << 10));     // 256 KB
    float* rowAcc = (float*)(ws + (512u << 10));     // 1024 f32 = 4 KB
    int*   tick   = (int*)(ws + (520u << 10));       // 32 ints
    float* buf    = (float*)(ws + (1u << 20));       // 4 x 1 MB fp32 buffers
    const unsigned MB = (1u << 20) / 4;
    float* hm0 = buf + 0 * MB;
    float* hm1 = buf + 1 * MB;
    float* hl0 = buf + 2 * MB;
    float* hl1 = buf + 3 * MB;

    k1_layer1<<<256, 256, 0, stream>>>(x, w1m, w1l, b1m, b1l,
                                       hm0, hm1, hl0, hl1,
                                       y, zs, pA1, pB1, rowAcc, tick, out);
    k2_fused<<<256, 256, 0, stream>>>(hm0, hm1, hl0, hl1,
                                      w2m, w2l, b2m, b2l,
                                      y, zs, pA1, pB1, rowAcc, tick, out);
}

// Round 8
// 100.486 us; speedup vs baseline: 1.1198x; 1.1198x over previous
//
#include <hip/hip_runtime.h>
#include <math.h>

// N=1024, X_DIM=HID=Y_DIM=256. 3 launches, 256 blocks each.
// R8: split conversion moved upstream. K1 computes full-K layer-1 (64x32
// tiles, 2 heads), applies bias+relu, stores h as bf16 hi/lo; also pre-splits
// w2. K2 is conversion-free (ushort4 staging + MFMA only). K3 = R6 epilogue.
constexpr int LSB = 72;  // bf16 LDS row stride (144 B) — benign banks (R6 proven)

typedef short bf16x8 __attribute__((ext_vector_type(8)));
typedef float f32x4  __attribute__((ext_vector_type(4)));

__device__ __forceinline__ unsigned short f2bf_rne(float f) {
    unsigned u = __float_as_uint(f);
    unsigned r = (u + 0x7fff + ((u >> 16) & 1)) >> 16;
    return (unsigned short)r;
}
__device__ __forceinline__ float bf2f(unsigned short h) {
    return __uint_as_float(((unsigned)h) << 16);
}
__device__ __forceinline__ void split4(float4 v, ushort4& hi, ushort4& lo) {
    hi.x = f2bf_rne(v.x); lo.x = f2bf_rne(v.x - bf2f(hi.x));
    hi.y = f2bf_rne(v.y); lo.y = f2bf_rne(v.y - bf2f(hi.y));
    hi.z = f2bf_rne(v.z); lo.z = f2bf_rne(v.z - bf2f(hi.z));
    hi.w = f2bf_rne(v.w); lo.w = f2bf_rne(v.w - bf2f(hi.w));
}

// Block decode (both GEMM kernels): head=bid&1, colTile=(bid>>1)&7 (32 wide),
// rowTile=bid>>4 (64 tall). 16*8*2 = 256 blocks, full K=256.

// ---------------------------------------------------------------------------
// K1: layer-1 GEMM, 64x32 tile, K=256, MFMA bf16 split-fp32 (hh+hl+lh).
// Epilogue: bias+relu -> Dekker split -> ushort hi/lo stores (h for K2).
// Extras per block: 256-elem w2m/w2l split, 4-row moment partials, out zero.
// ---------------------------------------------------------------------------
__global__ __launch_bounds__(256)
void k1_layer1(const float* __restrict__ x,
               const float* __restrict__ w1m, const float* __restrict__ w1l,
               const float* __restrict__ b1m, const float* __restrict__ b1l,
               const float* __restrict__ w2m, const float* __restrict__ w2l,
               unsigned short* __restrict__ hmH, unsigned short* __restrict__ hmL,
               unsigned short* __restrict__ hlH, unsigned short* __restrict__ hlL,
               unsigned short* __restrict__ w2mH, unsigned short* __restrict__ w2mL,
               unsigned short* __restrict__ w2lH, unsigned short* __restrict__ w2lL,
               const float* __restrict__ y, const float* __restrict__ z,
               float* __restrict__ pA1, float* __restrict__ pB1,
               float* __restrict__ out) {
    const int bid = blockIdx.x, t = threadIdx.x;
    const int head = bid & 1, ct = (bid >> 1) & 7, rt = bid >> 4;
    const int rowBase = rt * 64, colBase = ct * 32;
    const int w = t >> 6, lane = t & 63, quad = lane >> 4, mr = lane & 15;

    const float* Bw   = head ? w1l : w1m;
    const float* bias = head ? b1l : b1m;
    unsigned short* CH = head ? hlH : hmH;
    unsigned short* CL = head ? hlL : hmL;

    __shared__ __align__(16) unsigned short Ah[64][LSB], Al[64][LSB];
    __shared__ __align__(16) unsigned short Bh[32][LSB], Bl[32][LSB];

    f32x4 acc[2] = {{0.f, 0.f, 0.f, 0.f}, {0.f, 0.f, 0.f, 0.f}};

    for (int kt = 0; kt < 256; kt += 64) {
#pragma unroll
        for (int p = 0; p < 4; p++) {
            int idx = p * 256 + t;
            int r = idx >> 4, k4 = idx & 15;
            float4 av = *(const float4*)&x[(rowBase + r) * 256 + kt + k4 * 4];
            ushort4 h4, l4;
            split4(av, h4, l4);
            *(ushort4*)&Ah[r][k4 * 4] = h4;
            *(ushort4*)&Al[r][k4 * 4] = l4;
            if (p < 2) {   // r in [0,32) here
                float4 bv = *(const float4*)&Bw[(colBase + r) * 256 + kt + k4 * 4];
                split4(bv, h4, l4);
                *(ushort4*)&Bh[r][k4 * 4] = h4;
                *(ushort4*)&Bl[r][k4 * 4] = l4;
            }
        }
        __syncthreads();

#pragma unroll
        for (int kk = 0; kk < 64; kk += 32) {
            int ko = kk + quad * 8;
            bf16x8 ah = *(const bf16x8*)&Ah[w * 16 + mr][ko];
            bf16x8 al = *(const bf16x8*)&Al[w * 16 + mr][ko];
#pragma unroll
            for (int nt = 0; nt < 2; nt++) {
                bf16x8 bh = *(const bf16x8*)&Bh[nt * 16 + mr][ko];
                bf16x8 bl = *(const bf16x8*)&Bl[nt * 16 + mr][ko];
                acc[nt] = __builtin_amdgcn_mfma_f32_16x16x32_bf16(ah, bh, acc[nt], 0, 0, 0);
                acc[nt] = __builtin_amdgcn_mfma_f32_16x16x32_bf16(ah, bl, acc[nt], 0, 0, 0);
                acc[nt] = __builtin_amdgcn_mfma_f32_16x16x32_bf16(al, bh, acc[nt], 0, 0, 0);
            }
        }
        __syncthreads();
    }

    // epilogue: bias + relu -> split -> hi/lo ushort stores
    // C/D layout: col = lane&15, row = quad*4 + reg (HW-verified)
#pragma unroll
    for (int nt = 0; nt < 2; nt++) {
        int cg = colBase + nt * 16 + mr;
        float bb = bias[cg];
#pragma unroll
        for (int reg = 0; reg < 4; reg++) {
            int rg = rowBase + w * 16 + quad * 4 + reg;
            float v = fmaxf(acc[nt][reg] + bb, 0.f);
            unsigned short hi = f2bf_rne(v);
            CH[rg * 256 + cg] = hi;
            CL[rg * 256 + cg] = f2bf_rne(v - bf2f(hi));
        }
    }

    // w2 pre-split: 1 elem/thread from each of w2m, w2l (256*256 total each)
    {
        int off = bid * 256 + t;
        float vm = w2m[off], vl = w2l[off];
        unsigned short h1 = f2bf_rne(vm);
        w2mH[off] = h1; w2mL[off] = f2bf_rne(vm - bf2f(h1));
        unsigned short h2 = f2bf_rne(vl);
        w2lH[off] = h2; w2lL[off] = f2bf_rne(vl - bf2f(h2));
    }

    // moment partials over rows [4*bid, 4*bid+4)
    {
        float sA = 0.f, sB = 0.f;
        int base = bid * 4 * 256 + t;
#pragma unroll
        for (int j = 0; j < 4; j++) {
            float yv = y[base + j * 256];
            float zv = z[base + j * 256];
            sA += yv * yv + zv * zv;
            sB += yv + zv;
        }
        pA1[bid * 256 + t] = sA;
        pB1[bid * 256 + t] = sB;
    }
    if (bid == 0 && t == 0) out[0] = 0.f;
}

// ---------------------------------------------------------------------------
// K2: layer-2 GEMM, 64x32 tile, K=256, conversion-free: A = h (bf16 hi/lo),
// B = pre-split w2. Writes full mu/lv fp32. Blocks 0..15 fold moments 256->16.
// ---------------------------------------------------------------------------
__global__ __launch_bounds__(256)
void k2_layer2(const unsigned short* __restrict__ hmH, const unsigned short* __restrict__ hmL,
               const unsigned short* __restrict__ hlH, const unsigned short* __restrict__ hlL,
               const unsigned short* __restrict__ w2mH, const unsigned short* __restrict__ w2mL,
               const unsigned short* __restrict__ w2lH, const unsigned short* __restrict__ w2lL,
               const float* __restrict__ b2m, const float* __restrict__ b2l,
               float* __restrict__ muO, float* __restrict__ lvO,
               const float* __restrict__ pA1, const float* __restrict__ pB1,
               float* __restrict__ pA2, float* __restrict__ pB2) {
    const int bid = blockIdx.x, t = threadIdx.x;
    const int head = bid & 1, ct = (bid >> 1) & 7, rt = bid >> 4;
    const int rowBase = rt * 64, colBase = ct * 32;
    const int w = t >> 6, lane = t & 63, quad = lane >> 4, mr = lane & 15;

    const unsigned short* AH = head ? hlH : hmH;
    const unsigned short* AL = head ? hlL : hmL;
    const unsigned short* BH = head ? w2lH : w2mH;
    const unsigned short* BL = head ? w2lL : w2mL;
    const float* bias = head ? b2l : b2m;
    float* C = head ? lvO : muO;

    __shared__ __align__(16) unsigned short Ah[64][LSB], Al[64][LSB];
    __shared__ __align__(16) unsigned short Bh[32][LSB], Bl[32][LSB];

    f32x4 acc[2] = {{0.f, 0.f, 0.f, 0.f}, {0.f, 0.f, 0.f, 0.f}};

    for (int kt = 0; kt < 256; kt += 64) {
#pragma unroll
        for (int p = 0; p < 4; p++) {
            int idx = p * 256 + t;
            int r = idx >> 4, k4 = idx & 15;
            int off = (rowBase + r) * 256 + kt + k4 * 4;
            *(ushort4*)&Ah[r][k4 * 4] = *(const ushort4*)&AH[off];
            *(ushort4*)&Al[r][k4 * 4] = *(const ushort4*)&AL[off];
            if (p < 2) {   // r in [0,32)
                int boff = (colBase + r) * 256 + kt + k4 * 4;
                *(ushort4*)&Bh[r][k4 * 4] = *(const ushort4*)&BH[boff];
                *(ushort4*)&Bl[r][k4 * 4] = *(const ushort4*)&BL[boff];
            }
        }
        __syncthreads();

#pragma unroll
        for (int kk = 0; kk < 64; kk += 32) {
            int ko = kk + quad * 8;
            bf16x8 ah = *(const bf16x8*)&Ah[w * 16 + mr][ko];
            bf16x8 al = *(const bf16x8*)&Al[w * 16 + mr][ko];
#pragma unroll
            for (int nt = 0; nt < 2; nt++) {
                bf16x8 bh = *(const bf16x8*)&Bh[nt * 16 + mr][ko];
                bf16x8 bl = *(const bf16x8*)&Bl[nt * 16 + mr][ko];
                acc[nt] = __builtin_amdgcn_mfma_f32_16x16x32_bf16(ah, bh, acc[nt], 0, 0, 0);
                acc[nt] = __builtin_amdgcn_mfma_f32_16x16x32_bf16(ah, bl, acc[nt], 0, 0, 0);
                acc[nt] = __builtin_amdgcn_mfma_f32_16x16x32_bf16(al, bh, acc[nt], 0, 0, 0);
            }
        }
        __syncthreads();
    }

#pragma unroll
    for (int nt = 0; nt < 2; nt++) {
        int cg = colBase + nt * 16 + mr;
        float bb = bias[cg];
#pragma unroll
        for (int reg = 0; reg < 4; reg++) {
            int rg = rowBase + w * 16 + quad * 4 + reg;
            C[rg * 256 + cg] = acc[nt][reg] + bb;
        }
    }

    // moment fold 256 -> 16 partial sets (blocks 0..15)
    if (bid < 16) {
        float sA = 0.f, sB = 0.f;
#pragma unroll
        for (int s = 0; s < 16; s++) {
            int o = (bid * 16 + s) * 256 + t;
            sA += pA1[o];
            sB += pB1[o];
        }
        pA2[bid * 256 + t] = sA;
        pB2[bid * 256 + t] = sB;
    }
}

// ---------------------------------------------------------------------------
// K3: epilogue (R6 proven). Fold 16 moment partials; per row i:
// diff = sum_o iv*(Mt - dy^2 - dz^2); out += relu(diff)/N. 256 blocks x 4 rows.
// ---------------------------------------------------------------------------
__global__ __launch_bounds__(256)
void k3_epilogue(const float* __restrict__ muO, const float* __restrict__ lvO,
                 const float* __restrict__ y, const float* __restrict__ z,
                 const float* __restrict__ pA2, const float* __restrict__ pB2,
                 float* __restrict__ out) {
    __shared__ float red[4];
    int t = threadIdx.x;
    int lane = t & 63, wave = t >> 6;

    float mA = 0.f, mB = 0.f;
#pragma unroll
    for (int g = 0; g < 16; g++) {
        mA += pA2[g * 256 + t];
        mB += pB2[g * 256 + t];
    }
    mA *= (1.f / 1024.f);   // mean_j (y^2+z^2)
    mB *= (1.f / 1024.f);   // mean_j (y+z)

    float blockSum = 0.f;
    for (int r = 0; r < 4; r++) {
        int o = (blockIdx.x * 4 + r) * 256 + t;
        float m  = muO[o];
        float lv = tanhf(lvO[o]);
        float iv = 0.5f * expf(-lv);       // 1/(2*exp(logvar))
        float yv = y[o];
        float zv = z[o];
        float Mt = mA - 2.f * m * mB + 2.f * m * m;
        float dy = m - yv, dz = m - zv;
        float term = iv * (Mt - dy * dy - dz * dz);
#pragma unroll
        for (int mask = 32; mask; mask >>= 1)
            term += __shfl_xor(term, mask, 64);
        if (lane == 0) red[wave] = term;
        __syncthreads();
        if (t == 0) {
            float rs = red[0] + red[1] + red[2] + red[3];
            blockSum += fmaxf(rs, 0.f);
        }
        __syncthreads();
    }
    if (t == 0) atomicAdd(out, blockSum * (1.f / 1024.f));
}

// ---------------------------------------------------------------------------
extern "C" void kernel_launch(void* const* d_in, const int* in_sizes, int n_in,
                              void* d_out, int out_size, void* d_ws, size_t ws_size,
                              hipStream_t stream) {
    const float* x   = (const float*)d_in[0];
    const float* y   = (const float*)d_in[1];
    const float* zs  = (const float*)d_in[2];
    const float* w1m = (const float*)d_in[3];
    const float* b1m = (const float*)d_in[4];
    const float* w2m = (const float*)d_in[5];
    const float* b2m = (const float*)d_in[6];
    const float* w1l = (const float*)d_in[7];
    const float* b1l = (const float*)d_in[8];
    const float* w2l = (const float*)d_in[9];
    const float* b2l = (const float*)d_in[10];
    float* out = (float*)d_out;

    char* ws = (char*)d_ws;
    float* pA1 = (float*)(ws);                         // 256 KB
    float* pB1 = (float*)(ws + (256u << 10));          // 256 KB
    float* pA2 = (float*)(ws + (512u << 10));          // 16 KB
    float* pB2 = (float*)(ws + (528u << 10));          // 16 KB
    unsigned short* hmH = (unsigned short*)(ws + (1024u << 10));  // 512 KB each
    unsigned short* hmL = (unsigned short*)(ws + (1536u << 10));
    unsigned short* hlH = (unsigned short*)(ws + (2048u << 10));
    unsigned short* hlL = (unsigned short*)(ws + (2560u << 10));
    unsigned short* w2mH = (unsigned short*)(ws + (3072u << 10)); // 128 KB each
    unsigned short* w2mL = (unsigned short*)(ws + (3200u << 10));
    unsigned short* w2lH = (unsigned short*)(ws + (3328u << 10));
    unsigned short* w2lL = (unsigned short*)(ws + (3456u << 10));
    float* muO = (float*)(ws + (4096u << 10));         // 1 MB
    float* lvO = (float*)(ws + (5120u << 10));         // 1 MB

    k1_layer1<<<256, 256, 0, stream>>>(x, w1m, w1l, b1m, b1l, w2m, w2l,
                                       hmH, hmL, hlH, hlL,
                                       w2mH, w2mL, w2lH, w2lL,
                                       y, zs, pA1, pB1, out);
    k2_layer2<<<256, 256, 0, stream>>>(hmH, hmL, hlH, hlL,
                                       w2mH, w2mL, w2lH, w2lL,
                                       b2m, b2l, muO, lvO,
                                       pA1, pB1, pA2, pB2);
    k3_epilogue<<<256, 256, 0, stream>>>(muO, lvO, y, zs, pA2, pB2, out);
}